// Round 1
// baseline (167.219 us; speedup 1.0000x reference)
//
#include <hip/hip_runtime.h>

typedef unsigned short u16;
typedef __attribute__((ext_vector_type(4)))  float f32x4;
typedef __attribute__((ext_vector_type(16))) float f32x16;
typedef __attribute__((ext_vector_type(8)))  short s16x8;   // 8 bf16 MFMA fragment
typedef __attribute__((ext_vector_type(4)))  unsigned short u16x4;

typedef const __attribute__((address_space(1))) void* gp1;
typedef __attribute__((address_space(3))) void* lp3;
#define GLOAD16(g, l) __builtin_amdgcn_global_load_lds((gp1)(g), (lp3)(l), 16, 0, 0)

__device__ __forceinline__ u16 f2bf(float f) {
    union { float f; unsigned u; } c; c.f = f;
    unsigned r = c.u + 0x7fffu + ((c.u >> 16) & 1u);   // RNE
    return (u16)(r >> 16);
}

// ---------------- fp32 -> bf16 cast (all 5 arrays, one launch) ----------------
__global__ void castall(const float* __restrict__ x,  const float* __restrict__ wq,
                        const float* __restrict__ wk, const float* __restrict__ wv,
                        const float* __restrict__ wp,
                        u16* __restrict__ xb,  u16* __restrict__ wqb, u16* __restrict__ wkb,
                        u16* __restrict__ wvb, u16* __restrict__ wpb) {
    int blk = blockIdx.x;
    const float* src; u16* dst; long off;
    if (blk < 2048) { src = x; dst = xb; off = (long)blk * 1024; }
    else {
        int w = (blk - 2048) >> 9, bb = (blk - 2048) & 511;
        src = (w == 0 ? wq : w == 1 ? wk : w == 2 ? wv : wp);
        dst = (w == 0 ? wqb : w == 1 ? wkb : w == 2 ? wvb : wpb);
        off = (long)bb * 1024;
    }
    long i = off + threadIdx.x * 4;
    f32x4 v = *(const f32x4*)(src + i);
    u16x4 o;
    o[0] = f2bf(v[0]); o[1] = f2bf(v[1]); o[2] = f2bf(v[2]); o[3] = f2bf(v[3]);
    *(u16x4*)(dst + i) = o;
}

// ---------------- QKV projection GEMM ----------------
// M=8192 (b*1024+s), N=6144 (w*2048 + h*256 + e), K=256.
// Q -> [B,H,S,256] linear bf16.
// K -> swizzled tile image: per bh, 32 tiles [32 rows(s)][256 cols(e)],
//      elem (r,c) at u16 idx r*256 + ((c&~7)^((r&7)<<3)) + (c&7).
// V -> PADDED tile image: per bh, 32 tiles [256 rows(e)][40 cols(j)], j<32 valid,
//      elem (e,j) at u16 idx e*40 + j. 80B rows -> bank-staggered, no swizzle.
__global__ __launch_bounds__(256) void qkv_gemm(
    const u16* __restrict__ xb,
    const u16* __restrict__ Wqb, const u16* __restrict__ Wkb, const u16* __restrict__ Wvb,
    const float* __restrict__ bq, const float* __restrict__ bk, const float* __restrict__ bv,
    u16* __restrict__ Qb, u16* __restrict__ Kimg, u16* __restrict__ Vimg)
{
    __shared__ u16 As[128 * 32];
    __shared__ u16 Bs[128 * 32];
    const int tid  = threadIdx.x;
    const int lane = tid & 63;
    const int li   = lane & 15, lg = lane >> 4;
    const int wave = tid >> 6;
    const int wr   = wave >> 1, wc = wave & 1;
    const int m0   = blockIdx.x * 128;
    const int n0g  = blockIdx.y * 128;
    const int w    = n0g >> 11;            // 0:Q 1:K 2:V
    const int h    = (n0g >> 8) & 7;
    const int e0   = n0g & 255;            // 0 or 128
    const u16* Wsel = (w == 0 ? Wqb : (w == 1 ? Wkb : Wvb)) + h * 65536;

    const int srow = tid >> 2;             // 0..63
    const int scol = (tid & 3) * 8;

    f32x4 acc[4][4] = {};

    for (int k0 = 0; k0 < 256; k0 += 32) {
        __syncthreads();
        #pragma unroll
        for (int i = 0; i < 2; ++i) {
            int row = i * 64 + srow;
            GLOAD16(&xb[(m0 + row) * 256 + k0 + scol],   &As[i * 2048 + tid * 8]);
            GLOAD16(&Wsel[(e0 + row) * 256 + k0 + scol], &Bs[i * 2048 + tid * 8]);
        }
        __syncthreads();
        s16x8 af[4], bf[4];
        #pragma unroll
        for (int mi = 0; mi < 4; ++mi)
            af[mi] = *(const s16x8*)&As[(wr * 64 + mi * 16 + li) * 32 + lg * 8];
        #pragma unroll
        for (int ni = 0; ni < 4; ++ni)
            bf[ni] = *(const s16x8*)&Bs[(wc * 64 + ni * 16 + li) * 32 + lg * 8];
        #pragma unroll
        for (int mi = 0; mi < 4; ++mi)
            #pragma unroll
            for (int ni = 0; ni < 4; ++ni)
                acc[mi][ni] = __builtin_amdgcn_mfma_f32_16x16x32_bf16(af[mi], bf[ni], acc[mi][ni], 0, 0, 0);
    }

    const int b  = m0 >> 10;
    const int s0 = m0 & 1023;
    if (w == 0) {
        const float* bp = bq + 256 * h;
        #pragma unroll
        for (int ni = 0; ni < 4; ++ni) {
            const int e = e0 + wc * 64 + ni * 16 + li;
            const float bias = bp[e];
            u16* obase = Qb + ((size_t)(b * 8 + h)) * 1024 * 256 + e;
            #pragma unroll
            for (int mi = 0; mi < 4; ++mi)
                #pragma unroll
                for (int r = 0; r < 4; ++r) {
                    int s = s0 + wr * 64 + mi * 16 + lg * 4 + r;
                    obase[(size_t)s * 256] = f2bf(acc[mi][ni][r] + bias);
                }
        }
    } else if (w == 1) {
        const float* bp = bk + 256 * h;
        u16* kb = Kimg + ((size_t)(b * 8 + h)) * 262144;
        #pragma unroll
        for (int ni = 0; ni < 4; ++ni) {
            const int e = e0 + wc * 64 + ni * 16 + li;
            const float bias = bp[e];
            #pragma unroll
            for (int mi = 0; mi < 4; ++mi)
                #pragma unroll
                for (int r = 0; r < 4; ++r) {
                    int s = s0 + wr * 64 + mi * 16 + lg * 4 + r;
                    int t = s >> 5, rr = s & 31;
                    size_t idx = (size_t)t * 8192 + rr * 256
                               + (((e & ~7) ^ ((rr & 7) << 3)) | (e & 7));
                    kb[idx] = f2bf(acc[mi][ni][r] + bias);
                }
        }
    } else {
        const float* bp = bv + 256 * h;
        u16* vb = Vimg + ((size_t)(b * 8 + h)) * 327680;
        #pragma unroll
        for (int ni = 0; ni < 4; ++ni) {
            const int e = e0 + wc * 64 + ni * 16 + li;
            const float bias = bp[e];
            #pragma unroll
            for (int mi = 0; mi < 4; ++mi) {
                int s = s0 + wr * 64 + mi * 16 + lg * 4;   // multiple of 4
                int t = s >> 5, cj = s & 31;
                size_t idx = (size_t)t * 10240 + e * 40 + cj;
                u16x4 pk;
                #pragma unroll
                for (int r = 0; r < 4; ++r) pk[r] = f2bf(acc[mi][ni][r] + bias);
                *(u16x4*)&vb[idx] = pk;
            }
        }
    }
}

// ---------------- flash attention ----------------
// 256 blocks = 64 (b,h) * 4 q-blocks; 8 waves (512 thr), 1 block/CU (108KB LDS).
//
// R9 pipeline (T15): per-iter order is QK(i) -> PV(i-1) -> softmax(i).
// PV(i-1) is independent of softmax(i), so the wave issues 32 MFMAs
// back-to-back and the softmax VALU chain executes in the shadow of the
// MFMA pipe drain (previously all 8 barrier-locked waves sat in softmax
// together and MfmaUtil capped at ~35%). paA/paB are consumed by PV(i-1)
// BEFORE softmax(i) overwrites them (WAR dep, no extra registers).
//
// Ledger: K unchanged from R8 — QK(i) in iter i reads kslot i%3; stage K
// tile min(i+3,31) into kslot i%3 after barrier-B; K-waves vmcnt(8) at top
// (12 outstanding, allow 2 newest -> tile i resident).
// V shifted one iter: PV(i-1) in iter i reads vslot (i-1)%3 == (i+2)%3;
// prologue stages V tiles 0,1 only; end of iter i stages V tile min(i+2,31)
// into vslot (i+2)%3 (freed this iter). V-waves vmcnt(10) at top: 15
// outstanding (tiles i-1,i,i+1), allow 2 newest -> tile i-1 resident.
// Iter 0 skips PV (uniform guard); PV(31) runs in an epilogue after
// V-waves vmcnt(10) + barrier (tile 31 sits in vslot 1; the clamped tail
// stages only touch slots 2 and 0).
// ds_read-vs-stage-write hazard closed as before: compiler lgkmcnt waits
// precede the last MFMA, which precedes barrier-B, so all slot reads
// complete before any wave's post-barrier stage writes.
__device__ __forceinline__ void softmax_pack(
    f32x16& sacc, float& m_run, float& l_run, f32x16* oacc,
    int hi, s16x8& paA, s16x8& paB)
{
    const float C = 0.09016844f;       // log2(e)/sqrt(256)
    const float THR = 16.0f;           // defer-max threshold (raw S units)
    float pm;
    {   // tree max: dependent depth 4 instead of 16
        float t[8];
        #pragma unroll
        for (int r = 0; r < 8; ++r) t[r] = fmaxf(sacc[r], sacc[r + 8]);
        #pragma unroll
        for (int r = 0; r < 4; ++r) t[r] = fmaxf(t[r], t[r + 4]);
        t[0] = fmaxf(t[0], t[2]); t[1] = fmaxf(t[1], t[3]);
        pm = fmaxf(t[0], t[1]);
    }
    pm = fmaxf(pm, __shfl_xor(pm, 32));
    if (!__all(pm - m_run <= THR)) {   // rare
        const float mnew = fmaxf(m_run, pm);
        const float corr = __builtin_amdgcn_exp2f((m_run - mnew) * C);
        l_run *= corr;
        #pragma unroll
        for (int r = 0; r < 16; ++r) {
            float rc = __shfl(corr, (r & 3) + 8 * (r >> 2) + 4 * hi);
            #pragma unroll
            for (int et = 0; et < 8; ++et) oacc[et][r] *= rc;
        }
        m_run = mnew;
    }
    #pragma unroll
    for (int r = 0; r < 16; ++r)
        sacc[r] = __builtin_amdgcn_exp2f((sacc[r] - m_run) * C);
    float psum;
    {   // tree sum
        float s[8];
        #pragma unroll
        for (int r = 0; r < 8; ++r) s[r] = sacc[r] + sacc[r + 8];
        #pragma unroll
        for (int r = 0; r < 4; ++r) s[r] = s[r] + s[r + 4];
        psum = (s[0] + s[1]) + (s[2] + s[3]);
    }
    psum += __shfl_xor(psum, 32);
    l_run += psum;
    unsigned dwA[4], dwB[4];
    #pragma unroll
    for (int c = 0; c < 4; ++c) {
        asm("v_cvt_pk_bf16_f32 %0, %1, %2" : "=v"(dwA[c]) : "v"(sacc[4*c]),   "v"(sacc[4*c+1]));
        asm("v_cvt_pk_bf16_f32 %0, %1, %2" : "=v"(dwB[c]) : "v"(sacc[4*c+2]), "v"(sacc[4*c+3]));
    }
    {
        unsigned a0 = dwA[0], a1 = dwA[1], b0 = dwB[0], b1 = dwB[1];
        asm("v_permlane32_swap_b32 %0, %1" : "+v"(a0), "+v"(a1));
        asm("v_permlane32_swap_b32 %0, %1" : "+v"(b0), "+v"(b1));
        union { unsigned u[4]; s16x8 v; } pk;
        pk.u[0] = a0; pk.u[1] = b0; pk.u[2] = a1; pk.u[3] = b1;
        paA = pk.v;
    }
    {
        unsigned a0 = dwA[2], a1 = dwA[3], b0 = dwB[2], b1 = dwB[3];
        asm("v_permlane32_swap_b32 %0, %1" : "+v"(a0), "+v"(a1));
        asm("v_permlane32_swap_b32 %0, %1" : "+v"(b0), "+v"(b1));
        union { unsigned u[4]; s16x8 v; } pk;
        pk.u[0] = a0; pk.u[1] = b0; pk.u[2] = a1; pk.u[3] = b1;
        paB = pk.v;
    }
}

// One pipelined iteration: QK(i) -> PV(i-1) [prev paA/paB] -> softmax(i).
__device__ __forceinline__ void attn_body(
    const int i, const u16* __restrict__ kt, const u16* __restrict__ vt,
    const s16x8 (&qf)[16], const int col, const int hi, const int ksw,
    f32x16* oacc, float& m_run, float& l_run, s16x8& paA, s16x8& paB)
{
    const int hi8 = hi * 8;
    f32x16 sacc = (f32x16){};
    __builtin_amdgcn_s_setprio(1);
    {   // QK(i): S[j=crow(r,hi)][q=col]
        const int rb_ = col * 256;
        #pragma unroll
        for (int dk = 0; dk < 16; ++dk) {
            s16x8 kf = *(const s16x8*)&kt[rb_ + ((dk * 16 + hi8) ^ ksw)];
            sacc = __builtin_amdgcn_mfma_f32_32x32x16_bf16(kf, qf[dk], sacc, 0, 0, 0);
        }
    }
    if (i > 0) {   // PV(i-1), independent of sacc -> fills MFMA pipe under softmax
        #pragma unroll
        for (int et = 0; et < 8; ++et) {
            s16x8 vf = *(const s16x8*)&vt[(et * 32 + col) * 40 + hi8];
            oacc[et] = __builtin_amdgcn_mfma_f32_32x32x16_bf16(paA, vf, oacc[et], 0, 0, 0);
        }
        #pragma unroll
        for (int et = 0; et < 8; ++et) {
            s16x8 vf = *(const s16x8*)&vt[(et * 32 + col) * 40 + 16 + hi8];
            oacc[et] = __builtin_amdgcn_mfma_f32_32x32x16_bf16(paB, vf, oacc[et], 0, 0, 0);
        }
    }
    __builtin_amdgcn_s_setprio(0);
    softmax_pack(sacc, m_run, l_run, oacc, hi, paA, paB);   // overwrites paA/paB (WAR)
}

__global__ __launch_bounds__(512, 2) void attn(
    const u16* __restrict__ Qb, const u16* __restrict__ Kimg,
    const u16* __restrict__ Vimg, u16* __restrict__ Ob)
{
    __shared__ u16 kbuf[3][8192];      // [32 j][256 d] swizzled, 16KB each
    __shared__ u16 vbuf[3][10240];     // [256 e][40 j] padded, 20KB each
    const int tid  = threadIdx.x;
    const int lane = tid & 63;
    const int wave = tid >> 6;
    const int col  = lane & 31;        // q-row for S, e-col for O
    const int hi   = lane >> 5;
    const int hi8  = hi * 8;
    const int ksw  = (lane & 7) << 3;  // K-read XOR swizzle
    // XCD swizzle: 256 blocks, 32 per XCD -> 8 distinct (b,h) per XCD
    const int bid  = ((blockIdx.x & 7) << 5) | (blockIdx.x >> 3);
    const int bh   = bid >> 2;
    const int qblk = bid & 3;
    const int q0   = qblk * 256 + wave * 32;   // wave's 32 q-rows

    const u16* qp = Qb + ((size_t)bh * 1024 + q0) * 256;
    const u16* kg = Kimg + (size_t)bh * 262144;
    const u16* vg = Vimg + (size_t)bh * 327680;

    // role-split staging: waves 0-3 -> K (4 loads/batch), 4-7 -> V (5 loads/batch)
    #define STAGEK(sl, t)                                                         \
        {                                                                         \
            const int s_ = (sl), t_ = (t);                                        \
            const size_t kb_ = (size_t)t_ * 8192 + tid * 8;                       \
            _Pragma("unroll")                                                     \
            for (int c_ = 0; c_ < 4; ++c_)                                        \
                GLOAD16(&kg[kb_ + c_ * 2048], &kbuf[s_][c_ * 2048 + tid * 8]);    \
        }
    #define STAGEV(sl, t)                                                         \
        {                                                                         \
            const int s_ = (sl), t_ = (t);                                        \
            const int vth_ = tid - 256;                                          \
            const size_t vb_ = (size_t)t_ * 10240 + vth_ * 8;                     \
            _Pragma("unroll")                                                     \
            for (int c_ = 0; c_ < 5; ++c_)                                        \
                GLOAD16(&vg[vb_ + c_ * 2048], &vbuf[s_][c_ * 2048 + vth_ * 8]);   \
        }

    // Q B-frags first (their vmcnt retires before the batches we count against)
    s16x8 qf[16];
    #pragma unroll
    for (int dk = 0; dk < 16; ++dk)
        qf[dk] = *(const s16x8*)&qp[(size_t)col * 256 + dk * 16 + hi8];

    // prologue: K tiles 0,1,2 (3 batches); V tiles 0,1 (2 batches — V is
    // consumed one iter later than K in the pipelined schedule)
    if (tid < 256) { STAGEK(0, 0); STAGEK(1, 1); STAGEK(2, 2); }
    else           { STAGEV(0, 0); STAGEV(1, 1); }

    f32x16 oacc[8] = {};               // O[q=crow(r,hi)][e=et*32+col]
    float m_run = -1e30f, l_run = 0.f;
    s16x8 paA = {}, paB = {};          // P-fragments of the PREVIOUS tile

    for (int i = 0; i < 32; ++i) {
        // counted wait: K-waves force tile i (QK), V-waves force tile i-1 (PV)
        if (tid < 256) { asm volatile("s_waitcnt vmcnt(8)"  ::: "memory"); }
        else           { asm volatile("s_waitcnt vmcnt(10)" ::: "memory"); }
        __builtin_amdgcn_s_barrier();              // barrier-A
        asm volatile("" ::: "memory");
        const int ks = i % 3;                      // K tile i
        const int vs = (i + 2) % 3;                // V tile i-1 ((i-1)%3 == (i+2)%3)
        attn_body(i, kbuf[ks], vbuf[vs], qf, col, hi, ksw,
                  oacc, m_run, l_run, paA, paB);
        asm volatile("" ::: "memory");
        __builtin_amdgcn_s_barrier();              // barrier-B: slot reads done
        asm volatile("" ::: "memory");
        const int ktile = (i + 3 < 32) ? (i + 3) : 31;   // clamp keeps count invariant
        const int vtile = (i + 2 < 32) ? (i + 2) : 31;
        if (tid < 256) { STAGEK(ks, ktile); }      // kslot i%3 just freed
        else           { STAGEV(vs, vtile); }      // vslot (i+2)%3 just freed
    }
    #undef STAGEK
    #undef STAGEV

    // epilogue: PV(31). V tile 31 is in vslot 31%3==1 (staged end of iter 29;
    // clamped tail stages only touched slots 2 and 0). paA/paB hold pa(31).
    if (tid >= 256) { asm volatile("s_waitcnt vmcnt(10)" ::: "memory"); }
    __builtin_amdgcn_s_barrier();
    asm volatile("" ::: "memory");
    {
        const u16* vt = vbuf[1];
        __builtin_amdgcn_s_setprio(1);
        #pragma unroll
        for (int et = 0; et < 8; ++et) {
            s16x8 vf = *(const s16x8*)&vt[(et * 32 + col) * 40 + hi8];
            oacc[et] = __builtin_amdgcn_mfma_f32_32x32x16_bf16(paA, vf, oacc[et], 0, 0, 0);
        }
        #pragma unroll
        for (int et = 0; et < 8; ++et) {
            s16x8 vf = *(const s16x8*)&vt[(et * 32 + col) * 40 + 16 + hi8];
            oacc[et] = __builtin_amdgcn_mfma_f32_32x32x16_bf16(paB, vf, oacc[et], 0, 0, 0);
        }
        __builtin_amdgcn_s_setprio(0);
    }

    // normalize + store: Ob [B,S,H*256]
    const float linv = 1.0f / l_run;
    const int b = bh >> 3, h = bh & 7;
    u16* op = Ob + ((size_t)b * 1024) * 2048 + h * 256;
    #pragma unroll
    for (int r = 0; r < 16; ++r) {
        const int crow = (r & 3) + 8 * (r >> 2) + 4 * hi;
        float lr = __shfl(linv, crow);
        const size_t row = q0 + crow;
        #pragma unroll
        for (int et = 0; et < 8; ++et)
            op[row * 2048 + et * 32 + col] = f2bf(oacc[et][r] * lr);
    }
}

// ---------------- output projection ----------------
// out[m, n] = sum_k Ob[m, k] * Wp[n, k]; M=8192, N=256, K=2048; fp32 out.
// BM=32, BN=128 -> grid 512 blocks (2 per CU). (R5 known-good version.)
__global__ __launch_bounds__(256) void out_gemm(
    const u16* __restrict__ Ob, const u16* __restrict__ Wpb, float* __restrict__ out)
{
    __shared__ u16 As[32 * 32];
    __shared__ u16 Bs[128 * 32];
    const int tid  = threadIdx.x;
    const int lane = tid & 63;
    const int li   = lane & 15, lg = lane >> 4;
    const int wave = tid >> 6;
    const int wr   = wave >> 1, wc = wave & 1;   // wave tile 16x64
    const int m0   = blockIdx.x * 32;
    const int n0   = blockIdx.y * 128;
    const int srow = tid >> 2;                   // 0..63
    const int scol = (tid & 3) * 8;

    f32x4 acc[4] = {};

    for (int k0 = 0; k0 < 2048; k0 += 32) {
        __syncthreads();
        if (tid < 128)
            GLOAD16(&Ob[(size_t)(m0 + srow) * 2048 + k0 + scol], &As[tid * 8]);
        #pragma unroll
        for (int i = 0; i < 2; ++i)
            GLOAD16(&Wpb[(size_t)(n0 + i * 64 + srow) * 2048 + k0 + scol],
                    &Bs[i * 2048 + tid * 8]);
        __syncthreads();
        s16x8 af, bf[4];
        af = *(const s16x8*)&As[(wr * 16 + li) * 32 + lg * 8];
        #pragma unroll
        for (int ni = 0; ni < 4; ++ni)
            bf[ni] = *(const s16x8*)&Bs[(wc * 64 + ni * 16 + li) * 32 + lg * 8];
        #pragma unroll
        for (int ni = 0; ni < 4; ++ni)
            acc[ni] = __builtin_amdgcn_mfma_f32_16x16x32_bf16(af, bf[ni], acc[ni], 0, 0, 0);
    }

    #pragma unroll
    for (int ni = 0; ni < 4; ++ni) {
        int n = n0 + wc * 64 + ni * 16 + li;
        #pragma unroll
        for (int r = 0; r < 4; ++r) {
            int m = m0 + wr * 16 + lg * 4 + r;
            out[(size_t)m * 256 + n] = acc[ni][r];
        }
    }
}

extern "C" void kernel_launch(void* const* d_in, const int* in_sizes, int n_in,
                              void* d_out, int out_size, void* d_ws, size_t ws_size,
                              hipStream_t stream) {
    const float* x  = (const float*)d_in[0];
    const float* Wq = (const float*)d_in[1];
    const float* Wk = (const float*)d_in[2];
    const float* Wv = (const float*)d_in[3];
    const float* bq = (const float*)d_in[4];
    const float* bk = (const float*)d_in[5];
    const float* bv = (const float*)d_in[6];
    const float* Wp = (const float*)d_in[7];
    float* out = (float*)d_out;

    u16* xb   = (u16*)d_ws;               // 2,097,152
    u16* Wqb  = xb   + (1u << 21);        // 524,288 each
    u16* Wkb  = Wqb  + (1u << 19);
    u16* Wvb  = Wkb  + (1u << 19);
    u16* Wpb  = Wvb  + (1u << 19);
    u16* Qb   = Wpb  + (1u << 19);        // 16,777,216
    u16* Kimg = Qb   + (1u << 24);        // 16,777,216
    u16* Vimg = Kimg + (1u << 24);        // 20,971,520 (padded V)
    u16* Ob   = Vimg + 20971520u;         // 16,777,216

    castall<<<4096, 256, 0, stream>>>(x, Wq, Wk, Wv, Wp, xb, Wqb, Wkb, Wvb, Wpb);
    qkv_gemm<<<dim3(64, 48), 256, 0, stream>>>(xb, Wqb, Wkb, Wvb, bq, bk, bv, Qb, Kimg, Vimg);
    attn<<<256, 512, 0, stream>>>(Qb, Kimg, Vimg, Ob);
    out_gemm<<<dim3(256, 2), 256, 0, stream>>>(Ob, Wpb, out);
}